// Round 5
// baseline (338.162 us; speedup 1.0000x reference)
//
#include <hip/hip_runtime.h>
#include <hip/hip_bf16.h>

#define K_DIM 4096
#define N_DIM 12288
#define B_DIM 64
#define G_DIM 64          // K / 64 groups
#define R_DIM 32
#define NT_DIM 768        // N / 16 n-tiles

typedef int v4i __attribute__((ext_vector_type(4)));

__device__ __forceinline__ int pack4(const v4i a) {
    return (a.x & 255) | ((a.y & 255) << 8) | ((a.z & 255) << 16) | (a.w << 24);
}

// ---------------------------------------------------------------------------
// Kernel 1: fused quantize + lora-down partial (R6 version — unchanged,
// proven in the 297.7 us baseline).
// ---------------------------------------------------------------------------
__global__ __launch_bounds__(256) void quant_lora_kernel(
    const float* __restrict__ x, const float* __restrict__ smooth,
    const float* __restrict__ ld, char* __restrict__ xq_p,
    float* __restrict__ ascale, float* __restrict__ t_part) {
    const int b = blockIdx.x >> 4;
    const int kc = blockIdx.x & 15;
    const int tid = threadIdx.x;
    const int k = kc * 256 + tid;

    __shared__ float sx[256];
    __shared__ float red[256];

    const float xd = x[b * K_DIM + k] / smooth[k];
    sx[tid] = xd;

    // --- quant (wave == group) ---
    const int lane = tid & 63;
    float a = fabsf(xd);
    #pragma unroll
    for (int off = 32; off; off >>= 1) a = fmaxf(a, __shfl_xor(a, off));
    const float as = fmaxf(a / 7.0f, 1e-8f);
    float q = rintf(xd / as);
    q = fminf(fmaxf(q, -8.0f), 7.0f);
    const int g = kc * 4 + (tid >> 6);
    const int bt = b >> 4, b15 = b & 15;
    const int quad = lane >> 4, kin = lane & 15;
    xq_p[((((size_t)bt * G_DIM + g) * 64) + quad * 16 + b15) * 16 + kin] = (char)(int)q;
    if (lane == 0) ascale[b * G_DIM + g] = as;
    __syncthreads();

    // --- lora-down partial over this 256-k chunk ---
    const int r = tid & 31, c = tid >> 5;     // c = 0..7
    const int kb = kc * 256 + c * 32;
    float acc = 0.f;
    #pragma unroll 8
    for (int kk = 0; kk < 32; ++kk)
        acc += sx[c * 32 + kk] * ld[(size_t)(kb + kk) * R_DIM + r];
    red[tid] = acc;
    __syncthreads();
    if (tid < 32) {
        float s = 0.f;
        #pragma unroll
        for (int c2 = 0; c2 < 8; ++c2) s += red[c2 * 32 + tid];
        t_part[kc * (B_DIM * R_DIM) + b * R_DIM + tid] = s;
    }
}

// ---------------------------------------------------------------------------
// Kernel 2: main — R11: barrier-free direct-load K-loop (R10 structure) with
// an explicit 4-DEEP register pipeline.
// R10 post-mortem: VGPR_Count=52 proved the compiler kept only ~1 group's
// loads in flight -> ~600cy vmcnt stall per group -> 885 GB/s, 121.9 us,
// latency-bound (MfmaUtil 1%, VALUBusy 13%). FETCH=105 MB confirmed L1/L2
// absorb the 4x intra-block bq redundancy (no traffic blowup).
// Occupancy note: grid=768 = exactly 3 blocks/CU -> 12 waves/CU for ANY
// VGPR <= 170 (the R7 cliff). Registers 52->~170 are FREE; spend them:
// 4 named stage buffers (A,B,C,D; static indexing, rule #20), each
// {4x dwordx4 weights + 1x dwordx4 xa} = 20 VGPR. Issue order gives
// steady-state vmcnt(15) waits: 15 KB/wave = 180 KB/CU outstanding >> the
// ~6 KB needed to sustain the 10.2 B/cy/CU HBM share at ~600cy latency.
// No LDS for weights, no K-loop barriers -> same race-free class as R10.
// ---------------------------------------------------------------------------
__global__ __launch_bounds__(256) void main_fused_kernel(
    const int* __restrict__ qw, const float* __restrict__ wscales,
    const v4i* __restrict__ xq_p, const float* __restrict__ ascale,
    const float* __restrict__ t_part, const float* __restrict__ lora_up,
    const float* __restrict__ bias, float* __restrict__ out) {
    __shared__ float s_ws[G_DIM * 16];      // [g][j]   4 KB
    __shared__ float s_as[G_DIM * 68];      // [g][b]  17 KB (pad 68)
    __shared__ float s_t[B_DIM * R_DIM];    // [b][r]   8 KB

    const int nt = blockIdx.x;
    const int n0 = nt * 16;
    const int tid = threadIdx.x;

    // one-time LDS stages
    for (int i = tid; i < G_DIM * 16; i += 256)
        s_ws[i] = wscales[(i >> 4) * N_DIM + n0 + (i & 15)];
    for (int i = tid; i < B_DIM * G_DIM; i += 256) {
        const int b = i >> 6, g = i & 63;
        s_as[g * 68 + b] = ascale[i];
    }
    for (int i = tid; i < B_DIM * R_DIM; i += 256) {
        float s = 0.f;
        #pragma unroll
        for (int kc = 0; kc < 16; ++kc) s += t_part[kc * (B_DIM * R_DIM) + i];
        s_t[i] = s;
    }
    __syncthreads();                        // the ONLY block barrier

    const int w = tid >> 6, lane = tid & 63;
    const int col = lane & 15, quad = lane >> 4;

    float facc[4] = {0.f, 0.f, 0.f, 0.f};
    const v4i zero = {0, 0, 0, 0};
    const v4i* xbase = xq_p + (size_t)w * G_DIM * 64 + lane;          // [w][g][lane]
    const int* bsrc = qw + (size_t)(n0 + col) * K_DIM + quad * 16;    // per-lane row

#define DECL_STAGE(S) v4i S##w0, S##w1, S##w2, S##w3, S##xa;
#define LOADS(S, G)                                                          \
    {                                                                        \
        const int* p_ = bsrc + (G) * 64;                                     \
        S##w0 = *(const v4i*)(p_);                                           \
        S##w1 = *(const v4i*)(p_ + 4);                                       \
        S##w2 = *(const v4i*)(p_ + 8);                                       \
        S##w3 = *(const v4i*)(p_ + 12);                                      \
        S##xa = xbase[(size_t)(G) * 64];                                     \
    }
#define COMP(S, G)                                                           \
    {                                                                        \
        v4i bq;                                                              \
        bq.x = pack4(S##w0); bq.y = pack4(S##w1);                            \
        bq.z = pack4(S##w2); bq.w = pack4(S##w3);                            \
        const v4i d =                                                        \
            __builtin_amdgcn_mfma_i32_16x16x64_i8(S##xa, bq, zero, 0, 0, 0); \
        const float wsc = s_ws[(G) * 16 + col];                              \
        const float4 as4 =                                                   \
            *(const float4*)&s_as[(G) * 68 + w * 16 + quad * 4];             \
        facc[0] = fmaf(as4.x * wsc, (float)d[0], facc[0]);                   \
        facc[1] = fmaf(as4.y * wsc, (float)d[1], facc[1]);                   \
        facc[2] = fmaf(as4.z * wsc, (float)d[2], facc[2]);                   \
        facc[3] = fmaf(as4.w * wsc, (float)d[3], facc[3]);                   \
    }

    DECL_STAGE(A) DECL_STAGE(B) DECL_STAGE(C) DECL_STAGE(D)
    LOADS(A, 0) LOADS(B, 1) LOADS(C, 2) LOADS(D, 3)

    for (int g = 0; g < 60; g += 4) {
        COMP(A, g);     LOADS(A, g + 4);
        COMP(B, g + 1); LOADS(B, g + 5);
        COMP(C, g + 2); LOADS(C, g + 6);
        COMP(D, g + 3); LOADS(D, g + 7);
    }
    // tail: groups 60..63 already resident in A..D
    COMP(A, 60); COMP(B, 61); COMP(C, 62); COMP(D, 63);

#undef DECL_STAGE
#undef LOADS
#undef COMP

    // ---- epilogue: bias + rank-32 lora, direct store ----
    const int n = n0 + col;
    float4 lu[8];
    {
        const float4* lp = (const float4*)(lora_up + (size_t)n * R_DIM);
        #pragma unroll
        for (int i = 0; i < 8; ++i) lu[i] = lp[i];
    }
    const float bs = bias[n];
    #pragma unroll
    for (int r = 0; r < 4; ++r) {
        const int b = w * 16 + quad * 4 + r;
        float acc = facc[r] + bs;
        #pragma unroll
        for (int r2 = 0; r2 < 8; ++r2) {
            const float4 tv = *(const float4*)&s_t[b * R_DIM + r2 * 4];
            acc += tv.x * lu[r2].x + tv.y * lu[r2].y +
                   tv.z * lu[r2].z + tv.w * lu[r2].w;
        }
        out[(size_t)b * N_DIM + n] = acc;
    }
}

// ---------------------------------------------------------------------------
extern "C" void kernel_launch(void* const* d_in, const int* in_sizes, int n_in,
                              void* d_out, int out_size, void* d_ws, size_t ws_size,
                              hipStream_t stream) {
    const float* x         = (const float*)d_in[0];
    const int*   q_w       = (const int*)d_in[1];
    const float* wscales   = (const float*)d_in[2];
    const float* lora_down = (const float*)d_in[3];
    const float* lora_up   = (const float*)d_in[4];
    const float* smooth    = (const float*)d_in[5];
    const float* bias      = (const float*)d_in[6];
    float* out = (float*)d_out;

    char*  xq     = (char*)d_ws;                            // 256 KB packed acts
    float* ascale = (float*)((char*)d_ws + 262144);         // 16 KB
    float* t_part = (float*)((char*)d_ws + 262144 + 16384); // 128 KB (16 slices)

    quant_lora_kernel<<<B_DIM * 16, 256, 0, stream>>>(x, smooth, lora_down,
                                                      xq, ascale, t_part);
    main_fused_kernel<<<NT_DIM, 256, 0, stream>>>(q_w, wscales, (const v4i*)xq,
                                                  ascale, t_part, lora_up, bias, out);
}